// Round 6
// baseline (3740.352 us; speedup 1.0000x reference)
//
#include <hip/hip_runtime.h>
#include <cfloat>
#include <climits>

#define T_TOKENS 65536
#define K_EMB 4096
#define D_DIM 256
#define QOFF ((size_t)T_TOKENS * D_DIM)   // 16777216
#define BT 128        // tokens per block
#define KHALF 2048    // codes per k-split half
#define NCHUNK 128    // 16 k-tiles x 8 d-chunks
#define ET_OFF (BT * 32)   // float offset of e-tile in LDS

// async global->LDS, 16 B per lane, dest = base + lane*16 (wave-uniform base)
__device__ __forceinline__ void async_cp16(float* lds, const float* g) {
    __builtin_amdgcn_global_load_lds(
        (const __attribute__((address_space(1))) unsigned int*)g,
        (__attribute__((address_space(3))) unsigned int*)lds, 16, 0, 0);
}

// fp32 multiply, contraction into later add blocked (numpy rounds the square first)
__device__ __forceinline__ float fmul_nc(float a, float b) {
    float c = a * b;
    asm volatile("" : "+v"(c));
    return c;
}

__device__ __forceinline__ double wave_sum_d(double v) {
#pragma unroll
    for (int o = 32; o >= 1; o >>= 1) v += __shfl_down(v, o, 64);
    return v;
}

// A32[t] = np.float32 pairwise sum of z[t]**2 (two 128-halves, 8 strided
// accumulators, ((r0+r1)+(r2+r3))+((r4+r5)+(r6+r7)), then h0+h1). Validated r4.
__global__ __launch_bounds__(256)
void a32_kernel(const float* __restrict__ z, float* __restrict__ a32) {
    __shared__ float lds[64][257];
    const int tid = threadIdx.x;
    const int t0 = blockIdx.x * 256;
    for (int sub = 0; sub < 4; sub++) {
        const int tb = t0 + sub * 64;
        __syncthreads();
        for (int idx = tid; idx < 64 * 256; idx += 256) {
            const int r = idx >> 8, c = idx & 255;
            lds[r][c] = z[(size_t)(tb + r) * D_DIM + c];
        }
        __syncthreads();
        if (tid < 64) {
            const float* row = lds[tid];
            float S[2];
            for (int h = 0; h < 2; h++) {
                const float* p = row + h * 128;
                float r[8];
#pragma unroll
                for (int j = 0; j < 8; j++) r[j] = fmul_nc(p[j], p[j]);
                for (int m = 1; m < 16; m++) {
#pragma unroll
                    for (int j = 0; j < 8; j++) r[j] += fmul_nc(p[8 * m + j], p[8 * m + j]);
                }
                S[h] = ((r[0] + r[1]) + (r[2] + r[3])) + ((r[4] + r[5]) + (r[6] + r[7]));
            }
            a32[tb + tid] = S[0] + S[1];
        }
    }
}

// C32[k] = fp32(||e_k||^2) — the +C add is annihilated by fp32 rounding anyway.
__global__ void c32_kernel(const float* __restrict__ emb, float* __restrict__ c32) {
    const int k = blockIdx.x;
    const double v = (double)emb[(size_t)k * D_DIM + threadIdx.x];
    double s = wave_sum_d(v * v);
    __shared__ double wsm[4];
    const int lane = threadIdx.x & 63, w = threadIdx.x >> 6;
    if (lane == 0) wsm[w] = s;
    __syncthreads();
    if (threadIdx.x == 0) c32[k] = (float)(wsm[0] + wsm[1] + wsm[2] + wsm[3]);
}

// Argmin GEMM. XOR-swizzled unpadded LDS tiles filled by global_load_lds
// (zero staging VGPRs). LDS[row][quad c] holds global d-quad c^(row&7); reader
// picks quad q^(row&7) for ascending q -> per-(t,k) fp32 fmaf chain in strict
// d order 0..255 (bit-identical to the validated round-4 chain).
__global__ __launch_bounds__(256, 4)
void argmin_np_kernel(const float* __restrict__ z, const float* __restrict__ emb,
                      const float* __restrict__ a32, const float* __restrict__ c32,
                      float* __restrict__ bvo, int* __restrict__ bio)
{
    __shared__ union {
        float t[2 * BT * 32];                              // 32768 B
        struct { float rb[16][BT]; int ri[16][BT]; } m;    // 16384 B
    } sm;

    const int tid = threadIdx.x;
    const int tx = tid & 15;        // code group: codes 16j+tx
    const int ty = tid >> 4;        // token group: tokens 16i+ty
    const int t0 = blockIdx.x * BT;
    const int k0 = blockIdx.y * KHALF;

    const int wv = tid >> 6, ln = tid & 63;
    const int lrow = ln >> 3;                  // lane's row within 8-row group
    const int lcol = (ln & 7) ^ lrow;          // XOR-swizzled source d-quad
    const int laneoff = lrow * D_DIM + 4 * lcol;

    float a32r[8];
#pragma unroll
    for (int i = 0; i < 8; i++) a32r[i] = a32[t0 + 16 * i + ty];

    float bv[8];
    int bi[8];
#pragma unroll
    for (int i = 0; i < 8; i++) { bv[i] = FLT_MAX; bi[i] = INT_MAX; }

    float acc[8][8];
#pragma unroll
    for (int i = 0; i < 8; i++)
#pragma unroll
        for (int j = 0; j < 8; j++) acc[i][j] = 0.0f;

    const int abase = ty * 32;                 // av float base (row ty, +512*i)
    const int bbase = ET_OFF + tx * 32;        // bw float base (row tx, +512*j)
    const int acx = (ty & 7) * 4;
    const int bcx = (tx & 7) * 4;

#pragma unroll 1
    for (int ci = 0; ci < NCHUNK; ci++) {
        const int dc = (ci & 7) * 32;
        const int kb = k0 + (ci >> 3) * BT;
        __syncthreads();   // previous chunk's readers done
        {
            const float* zsrc = z + (size_t)(t0 + 32 * wv) * D_DIM + dc + laneoff;
            const float* esrc = emb + (size_t)(kb + 32 * wv) * D_DIM + dc + laneoff;
            float* zl = &sm.t[(32 * wv) * 32];
            float* el = &sm.t[ET_OFF + (32 * wv) * 32];
#pragma unroll
            for (int n = 0; n < 4; n++) {
                async_cp16(zl + n * 256, zsrc + (size_t)n * 8 * D_DIM);
                async_cp16(el + n * 256, esrc + (size_t)n * 8 * D_DIM);
            }
        }
        __syncthreads();   // vmcnt(0) drain -> tile visible

#pragma unroll
        for (int q = 0; q < 8; q++) {
            const int ca = abase + (acx ^ (q * 4));
            const int cb = bbase + (bcx ^ (q * 4));
#pragma unroll
            for (int ih = 0; ih < 2; ih++) {   // i-split: caps live fragments
                float4 av[4];
#pragma unroll
                for (int ii = 0; ii < 4; ii++)
                    av[ii] = *(const float4*)&sm.t[ca + 512 * (4 * ih + ii)];
#pragma unroll
                for (int j = 0; j < 8; j++) {
                    const float4 bw = *(const float4*)&sm.t[cb + 512 * j];
#pragma unroll
                    for (int ii = 0; ii < 4; ii++) {
                        const int i = 4 * ih + ii;
                        acc[i][j] = fmaf(av[ii].x, bw.x, acc[i][j]);
                        acc[i][j] = fmaf(av[ii].y, bw.y, acc[i][j]);
                        acc[i][j] = fmaf(av[ii].z, bw.z, acc[i][j]);
                        acc[i][j] = fmaf(av[ii].w, bw.w, acc[i][j]);
                    }
                }
            }
        }

        if ((ci & 7) == 7) {   // k-tile epilogue: V = fl32(fl32(A-2M)+C), argmin
#pragma unroll
            for (int j = 0; j < 8; j++) {
                const int k = kb + 16 * j + tx;   // per-thread k strictly ascending
                const float ck = c32[k];
#pragma unroll
                for (int i = 0; i < 8; i++) {
                    const float v1 = a32r[i] - 2.0f * acc[i][j];
                    const float v2 = v1 + ck;
                    if (v2 < bv[i]) { bv[i] = v2; bi[i] = k; }
                    acc[i][j] = 0.0f;
                }
            }
        }
    }

    __syncthreads();   // tiles dead; reuse LDS for merge
#pragma unroll
    for (int i = 0; i < 8; i++) {
        sm.m.rb[tx][16 * i + ty] = bv[i];
        sm.m.ri[tx][16 * i + ty] = bi[i];
    }
    __syncthreads();
    if (tid < BT) {
        float B = sm.m.rb[0][tid];
        int I = sm.m.ri[0][tid];
#pragma unroll
        for (int e = 1; e < 16; e++) {
            const float cv = sm.m.rb[e][tid];
            const int ci2 = sm.m.ri[e][tid];
            if (cv < B || (cv == B && ci2 < I)) { B = cv; I = ci2; }
        }
        bvo[(size_t)blockIdx.y * T_TOKENS + t0 + tid] = B;
        bio[(size_t)blockIdx.y * T_TOKENS + t0 + tid] = I;
    }
}

// Merge k-split halves, gather quantized rows, write indices, fp64 loss partials.
__global__ __launch_bounds__(256)
void gather_kernel(const float* __restrict__ z, const float* __restrict__ emb,
                   const float* __restrict__ bvh, const int* __restrict__ bih,
                   float* __restrict__ out, double* __restrict__ partials)
{
    const int tid = threadIdx.x;
    const int base = blockIdx.x * 64;
    __shared__ double lsm[4];
    double lacc = 0.0;
    for (int ti = 0; ti < 64; ti++) {
        const int t = base + ti;
        // numpy first-index: tie -> half 0 (its ks are all smaller)
        const int sel = (bvh[T_TOKENS + t] < bvh[t]) ? bih[T_TOKENS + t] : bih[t];
        const float ev = emb[(size_t)sel * D_DIM + tid];
        const float zv = z[(size_t)t * D_DIM + tid];
        out[(size_t)t * D_DIM + tid] = ev;
        if (tid == 0) out[QOFF + t] = (float)sel;
        const double df = (double)zv - (double)ev;
        lacc += df * df;
    }
    lacc = wave_sum_d(lacc);
    const int lane = tid & 63, w = tid >> 6;
    if (lane == 0) lsm[w] = lacc;
    __syncthreads();
    if (tid == 0) partials[blockIdx.x] = lsm[0] + lsm[1] + lsm[2] + lsm[3];
}

__global__ void finalize_kernel(const double* __restrict__ partials, float* __restrict__ out) {
    __shared__ double rsm[4];
    const int tid = threadIdx.x;
    double s = 0.0;
    for (int i = tid; i < 1024; i += 256) s += partials[i];
    s = wave_sum_d(s);
    if ((tid & 63) == 0) rsm[tid >> 6] = s;
    __syncthreads();
    if (tid == 0) {
        const double mean = (rsm[0] + rsm[1] + rsm[2] + rsm[3]) / (double)QOFF;
        out[QOFF + T_TOKENS] = (float)(1.25 * mean);
    }
}

extern "C" void kernel_launch(void* const* d_in, const int* in_sizes, int n_in,
                              void* d_out, int out_size, void* d_ws, size_t ws_size,
                              hipStream_t stream)
{
    const float* z = (const float*)d_in[0];
    const float* emb = (const float*)d_in[1];
    float* out = (float*)d_out;
    char* ws = (char*)d_ws;

    float* a32 = (float*)ws;                          // 262144 B
    float* c32 = (float*)(ws + 262144);               // 16384 B
    float* bvh = (float*)(ws + 278528);               // 2*65536*4 = 524288 B
    int* bih = (int*)(ws + 802816);                   // 524288 B
    double* partials = (double*)(ws + 1327104);       // 8192 B

    a32_kernel<<<T_TOKENS / 256, 256, 0, stream>>>(z, a32);
    c32_kernel<<<K_EMB, 256, 0, stream>>>(emb, c32);
    argmin_np_kernel<<<dim3(T_TOKENS / BT, 2), 256, 0, stream>>>(z, emb, a32, c32, bvh, bih);
    gather_kernel<<<T_TOKENS / 64, 256, 0, stream>>>(z, emb, bvh, bih, out, partials);
    finalize_kernel<<<1, 256, 0, stream>>>(partials, out);
}